// Round 6
// baseline (184.285 us; speedup 1.0000x reference)
//
#include <hip/hip_runtime.h>

#define NN 8192
#define FIN 256
#define FOUT 128
#define BKJ 128            /* j per step */
#define LALPHA 0.2f

typedef short bf16x8 __attribute__((ext_vector_type(8)));
typedef float f32x4 __attribute__((ext_vector_type(4)));

#define FOR8(X) X(0) X(1) X(2) X(3) X(4) X(5) X(6) X(7)

static __device__ __forceinline__ unsigned short f2bf(float f) {
    unsigned u = __float_as_uint(f);
    u += 0x7FFFu + ((u >> 16) & 1u);   // RNE
    return (unsigned short)(u >> 16);
}
static __device__ __forceinline__ float bf2f(unsigned short b) {
    return __uint_as_float(((unsigned)b) << 16);
}

// ---------------- K1: Wh = h@W (f32), si = Wh@a1, sj = Wh@a2, WhT bf16 ----------------
__global__ __launch_bounds__(256) void gat_k1(
    const float* __restrict__ h, const float* __restrict__ W,
    const float* __restrict__ a, unsigned short* __restrict__ WhT,
    float* __restrict__ si, float* __restrict__ sj)
{
    __shared__ float Wt[64 * 128];          // 32 KB: W chunk [64k][128c]
    __shared__ float hT[64 * 36 + 4];       // 9 KB: h chunk transposed [64k][32r] pad 36
    const int t = threadIdx.x;
    const int r0 = blockIdx.x * 32;
    const int rg = t >> 5;    // rows rg*4..+4
    const int cg = t & 31;    // cols cg*4..+4
    float acc[4][4] = {{0.f,0.f,0.f,0.f},{0.f,0.f,0.f,0.f},{0.f,0.f,0.f,0.f},{0.f,0.f,0.f,0.f}};

    for (int kc = 0; kc < 4; ++kc) {
        __syncthreads();
        const float4* Ws = (const float4*)(W + kc * 64 * FOUT);
        float4* Wd = (float4*)Wt;
        #pragma unroll
        for (int v = 0; v < 8; ++v) Wd[v * 256 + t] = Ws[v * 256 + t];
        {
            const int hr = t >> 3, hk = (t & 7) * 8;
            const float* hs = h + (size_t)(r0 + hr) * FIN + kc * 64 + hk;
            float4 x0 = *(const float4*)hs;
            float4 x1 = *(const float4*)(hs + 4);
            hT[(hk + 0) * 36 + hr] = x0.x; hT[(hk + 1) * 36 + hr] = x0.y;
            hT[(hk + 2) * 36 + hr] = x0.z; hT[(hk + 3) * 36 + hr] = x0.w;
            hT[(hk + 4) * 36 + hr] = x1.x; hT[(hk + 5) * 36 + hr] = x1.y;
            hT[(hk + 6) * 36 + hr] = x1.z; hT[(hk + 7) * 36 + hr] = x1.w;
        }
        __syncthreads();
        #pragma unroll 8
        for (int kk = 0; kk < 64; ++kk) {
            float4 hv4 = *(const float4*)&hT[kk * 36 + rg * 4];
            float4 wv4 = *(const float4*)&Wt[kk * 128 + cg * 4];
            float hv[4] = {hv4.x, hv4.y, hv4.z, hv4.w};
            float wv[4] = {wv4.x, wv4.y, wv4.z, wv4.w};
            #pragma unroll
            for (int rr = 0; rr < 4; ++rr)
                #pragma unroll
                for (int cc = 0; cc < 4; ++cc)
                    acc[rr][cc] = fmaf(hv[rr], wv[cc], acc[rr][cc]);
        }
    }
    float4 a1v4 = *(const float4*)(a + cg * 4);
    float4 a2v4 = *(const float4*)(a + FOUT + cg * 4);
    float a1v[4] = {a1v4.x, a1v4.y, a1v4.z, a1v4.w};
    float a2v[4] = {a2v4.x, a2v4.y, a2v4.z, a2v4.w};
    float ps[4], qs[4];
    #pragma unroll
    for (int rr = 0; rr < 4; ++rr) {
        float p = 0.f, q = 0.f;
        #pragma unroll
        for (int cc = 0; cc < 4; ++cc) {
            p = fmaf(acc[rr][cc], a1v[cc], p);
            q = fmaf(acc[rr][cc], a2v[cc], q);
        }
        ps[rr] = p; qs[rr] = q;
    }
    #pragma unroll
    for (int off = 1; off <= 16; off <<= 1) {
        #pragma unroll
        for (int rr = 0; rr < 4; ++rr) {
            ps[rr] += __shfl_xor(ps[rr], off);
            qs[rr] += __shfl_xor(qs[rr], off);
        }
    }
    if (cg == 0) {
        #pragma unroll
        for (int rr = 0; rr < 4; ++rr) {
            si[r0 + rg * 4 + rr] = ps[rr];
            sj[r0 + rg * 4 + rr] = qs[rr];
        }
    }
    #pragma unroll
    for (int cc = 0; cc < 4; ++cc) {
        ushort4 v;
        v.x = f2bf(acc[0][cc]); v.y = f2bf(acc[1][cc]);
        v.z = f2bf(acc[2][cc]); v.w = f2bf(acc[3][cc]);
        *(ushort4*)(WhT + (size_t)(cg * 4 + cc) * NN + r0 + rg * 4) = v;
    }
}

// ---------------- K1s: sjmax = max_j sj[j] (global, one scalar) ----------------
__global__ __launch_bounds__(256) void gat_k1s(
    const float* __restrict__ sj, float* __restrict__ sjmax)
{
    __shared__ float red[256];
    float m = -1e30f;
    for (int i = threadIdx.x; i < NN; i += 256) m = fmaxf(m, sj[i]);
    red[threadIdx.x] = m;
    __syncthreads();
    for (int o = 128; o > 0; o >>= 1) {
        if (threadIdx.x < o) red[threadIdx.x] = fmaxf(red[threadIdx.x], red[threadIdx.x + o]);
        __syncthreads();
    }
    if (threadIdx.x == 0) sjmax[0] = red[0];
}

// ---------------- K2: fixed-m masked softmax + P@Wh via MFMA ----------------
// Barrier-free, LDS-free: WhT (2MB) is L2-resident; each wave reads its own
// B-fragments directly from global (4-way sector-coalesced across kg lanes).
static __device__ __forceinline__ unsigned short pcalc(
    int a, float sjv, float si_l, float m_row, float& ls)
{
    float x = si_l + sjv;
    x = fmaxf(x, LALPHA * x);                 // leaky_relu
    float p = (a > 0) ? __expf(x - m_row) : 0.f;   // x <= m_row guaranteed
    unsigned short pb = f2bf(p);
    ls += bf2f(pb);                           // denominator matches bf16-rounded numerator
    return pb;
}

template<int JS, bool FINAL>
__global__ __launch_bounds__(256, 2) void gat_k2(
    const int* __restrict__ adj, const unsigned short* __restrict__ WhT,
    const float* __restrict__ si, const float* __restrict__ sj,
    const float* __restrict__ sjmaxp,
    float* __restrict__ lsum, float* __restrict__ Opart, float* __restrict__ out)
{
    const int JR_ = NN / JS;
    const int NST_ = JR_ / BKJ;
    const int t = threadIdx.x;
    const int w = t >> 6, l = t & 63;
    const int rb = (int)blockIdx.x / JS, js = (int)blockIdx.x % JS;
    const int iw = rb * 64 + w * 16;       // wave's 16 rows
    const int j0 = js * JR_;
    const int row = l & 15, kg = l >> 4;   // MFMA A-frag: row = l&15, k-slice = kg*8..+8

    const float si_l = si[iw + row];
    const float sjmax = sjmaxp[0];
    const float xm = si_l + sjmax;
    const float m_row = fmaxf(xm, LALPHA * xm);   // upper bound on every masked score of this row
    const float* sjb = sj + j0 + kg * 8;
    const int* adjb = adj + (size_t)(iw + row) * NN + j0 + kg * 8;

    // per-n B-fragment base: WhT[col = n*16+row][j0 + kg*8 + ...]
#define WB_D(n) const unsigned short* wb##n = WhT + (size_t)(n * 16 + row) * NN + j0 + kg * 8;
    FOR8(WB_D)

#define ADR_D(q) int4 adr##q;
    FOR8(ADR_D)
#define ADR_L0(q) adr##q = *(const int4*)(adjb + (q / 2) * 32 + (q % 2) * 4);
    FOR8(ADR_L0)

#define ACC_D(n) f32x4 acc##n = {0.f, 0.f, 0.f, 0.f};
    FOR8(ACC_D)
    float ls0 = 0.f, ls1 = 0.f, ls2 = 0.f, ls3 = 0.f;

#define ADR_LN(q) adr##q = *(const int4*)(adjb + so + (q / 2) * 32 + (q % 2) * 4);
#define P8(AF, A0, A1, sp, LSV) { \
    float4 s0_ = *(const float4*)(sp); float4 s1_ = *(const float4*)((sp) + 4); \
    AF[0] = (short)pcalc(A0.x, s0_.x, si_l, m_row, LSV); \
    AF[1] = (short)pcalc(A0.y, s0_.y, si_l, m_row, LSV); \
    AF[2] = (short)pcalc(A0.z, s0_.z, si_l, m_row, LSV); \
    AF[3] = (short)pcalc(A0.w, s0_.w, si_l, m_row, LSV); \
    AF[4] = (short)pcalc(A1.x, s1_.x, si_l, m_row, LSV); \
    AF[5] = (short)pcalc(A1.y, s1_.y, si_l, m_row, LSV); \
    AF[6] = (short)pcalc(A1.z, s1_.z, si_l, m_row, LSV); \
    AF[7] = (short)pcalc(A1.w, s1_.w, si_l, m_row, LSV); }
    // B-fragment loads, k-chunk kc: 8 bf16 at wb_n + s*BKJ + kc*32
#define FG_L0(n) int4 fg0##n = *(const int4*)(wb##n + sofs);
#define FG_L1(n) int4 fg1##n = *(const int4*)(wb##n + sofs + 32);
#define FG_L2(n) int4 fg2##n = *(const int4*)(wb##n + sofs + 64);
#define FG_L3(n) int4 fg3##n = *(const int4*)(wb##n + sofs + 96);
#define MM0(n) acc##n = __builtin_amdgcn_mfma_f32_16x16x32_bf16(af0, *(const bf16x8*)&fg0##n, acc##n, 0, 0, 0);
#define MM1(n) acc##n = __builtin_amdgcn_mfma_f32_16x16x32_bf16(af1, *(const bf16x8*)&fg1##n, acc##n, 0, 0, 0);
#define MM2(n) acc##n = __builtin_amdgcn_mfma_f32_16x16x32_bf16(af2, *(const bf16x8*)&fg2##n, acc##n, 0, 0, 0);
#define MM3(n) acc##n = __builtin_amdgcn_mfma_f32_16x16x32_bf16(af3, *(const bf16x8*)&fg3##n, acc##n, 0, 0, 0);

    #pragma unroll 1
    for (int s = 0; s < NST_; ++s) {
        const size_t sofs = (size_t)s * BKJ;
        // H1: issue B-frags kc=0,1 (latency hidden under score phase)
        FOR8(FG_L0)
        FOR8(FG_L1)
        // scores -> p (bf16) inline, 4 parallel ls chains
        bf16x8 af0, af1, af2, af3;
        {
            const float* spp = sjb + s * BKJ;
            P8(af0, adr0, adr1, spp,      ls0)
            P8(af1, adr2, adr3, spp + 32, ls1)
            P8(af2, adr4, adr5, spp + 64, ls2)
            P8(af3, adr6, adr7, spp + 96, ls3)
        }
        // adj prefetch for s+1 (one full step of latency slack)
        if (s + 1 < NST_) {
            const size_t so = (size_t)(s + 1) * BKJ;
            FOR8(ADR_LN)
        }
        // H2: issue B-frags kc=2,3; then consume h1 (covers h2 latency), then h2
        FOR8(FG_L2)
        FOR8(FG_L3)
        FOR8(MM0)
        FOR8(MM1)
        FOR8(MM2)
        FOR8(MM3)
    }

    float ls = (ls0 + ls1) + (ls2 + ls3);
    ls += __shfl_xor(ls, 16);
    ls += __shfl_xor(ls, 32);
    if (FINAL) {
        float lsr0 = __shfl(ls, kg * 4 + 0);
        float lsr1 = __shfl(ls, kg * 4 + 1);
        float lsr2 = __shfl(ls, kg * 4 + 2);
        float lsr3 = __shfl(ls, kg * 4 + 3);
#define FN_ROW(n) { size_t ob = (size_t)(iw + kg * 4) * FOUT + n * 16 + row; \
    float o0 = acc##n[0] / lsr0; out[ob]            = (o0 > 0.f) ? o0 : expm1f(o0); \
    float o1 = acc##n[1] / lsr1; out[ob + FOUT]     = (o1 > 0.f) ? o1 : expm1f(o1); \
    float o2 = acc##n[2] / lsr2; out[ob + 2 * FOUT] = (o2 > 0.f) ? o2 : expm1f(o2); \
    float o3 = acc##n[3] / lsr3; out[ob + 3 * FOUT] = (o3 > 0.f) ? o3 : expm1f(o3); }
        FOR8(FN_ROW)
    } else {
        if (l < 16) lsum[(size_t)js * NN + iw + l] = ls;
#define ST_ROW(n) { size_t ob = ((size_t)js * NN + iw + kg * 4) * FOUT + n * 16 + row; \
    Opart[ob] = acc##n[0]; Opart[ob + FOUT] = acc##n[1]; \
    Opart[ob + 2 * FOUT] = acc##n[2]; Opart[ob + 3 * FOUT] = acc##n[3]; }
        FOR8(ST_ROW)
    }
}

// ---------------- K3: merge j-splits (plain sums; shared fixed m), divide, ELU ----------------
__global__ __launch_bounds__(256) void gat_k3(
    const float* __restrict__ lsum, const float* __restrict__ Opart,
    float* __restrict__ out)
{
    const int t = threadIdx.x;
    const int i = (int)blockIdx.x * 2 + (t >> 7);
    const int f = t & 127;
    float den = lsum[i] + lsum[NN + i] + lsum[2 * NN + i] + lsum[3 * NN + i];
    size_t base = (size_t)i * FOUT + f;
    const size_t SP = (size_t)NN * FOUT;
    float num = Opart[base] + Opart[SP + base]
              + Opart[2 * SP + base] + Opart[3 * SP + base];
    float o = num / den;
    out[base] = (o > 0.f) ? o : expm1f(o);   // ELU, alpha=1
}

extern "C" void kernel_launch(void* const* d_in, const int* in_sizes, int n_in,
                              void* d_out, int out_size, void* d_ws, size_t ws_size,
                              hipStream_t stream) {
    const float* h  = (const float*)d_in[0];
    const int*  adj = (const int*)d_in[1];
    const float* W  = (const float*)d_in[2];
    const float* a  = (const float*)d_in[3];
    float* out = (float*)d_out;
    char* ws = (char*)d_ws;
    // ws: WhT 2MB | si 32KB | sj 32KB | sjmax 256B | lsum 128KB | Opart 16MB
    unsigned short* WhT = (unsigned short*)ws;
    float* si     = (float*)(ws + 2097152);
    float* sj     = (float*)(ws + 2129920);
    float* sjmax  = (float*)(ws + 2162688);
    float* lsum   = (float*)(ws + 2162944);
    float* Opart  = (float*)(ws + 2294016);
    const size_t need4 = 2294016 + (size_t)4 * NN * FOUT * 4;   // ~19.1 MB

    gat_k1<<<256, 256, 0, stream>>>(h, W, a, WhT, si, sj);
    gat_k1s<<<1, 256, 0, stream>>>(sj, sjmax);
    if (ws_size >= need4) {
        gat_k2<4, false><<<512, 256, 0, stream>>>(adj, WhT, si, sj, sjmax, lsum, Opart, out);
        gat_k3<<<4096, 256, 0, stream>>>(lsum, Opart, out);
    } else {
        gat_k2<1, true><<<128, 256, 0, stream>>>(adj, WhT, si, sj, sjmax, lsum, Opart, out);
    }
}

// Round 7
// 111.075 us; speedup vs baseline: 1.6591x; 1.6591x over previous
//
#include <hip/hip_runtime.h>

#define NN 8192
#define FIN 256
#define FOUT 128
#define BKJ 64             /* j per step */
#define JSPLIT 8
#define LALPHA 0.2f

typedef short bf16x8 __attribute__((ext_vector_type(8)));
typedef float f32x4 __attribute__((ext_vector_type(4)));

#define FOR8(X) X(0) X(1) X(2) X(3) X(4) X(5) X(6) X(7)
#define FOR4(X) X(0) X(1) X(2) X(3)

static __device__ __forceinline__ unsigned short f2bf(float f) {
    unsigned u = __float_as_uint(f);
    u += 0x7FFFu + ((u >> 16) & 1u);   // RNE
    return (unsigned short)(u >> 16);
}

// ---------------- K1: Wh = h@W (f32), si = Wh@a1, sj = Wh@a2, WhT bf16 ----------------
__global__ __launch_bounds__(256) void gat_k1(
    const float* __restrict__ h, const float* __restrict__ W,
    const float* __restrict__ a, unsigned short* __restrict__ WhT,
    float* __restrict__ si, float* __restrict__ sj)
{
    __shared__ float Wt[64 * 128];          // 32 KB: W chunk [64k][128c]
    __shared__ float hT[64 * 36 + 4];       // 9 KB: h chunk transposed [64k][32r] pad 36
    const int t = threadIdx.x;
    const int r0 = blockIdx.x * 32;
    const int rg = t >> 5;    // rows rg*4..+4
    const int cg = t & 31;    // cols cg*4..+4
    float acc[4][4] = {{0.f,0.f,0.f,0.f},{0.f,0.f,0.f,0.f},{0.f,0.f,0.f,0.f},{0.f,0.f,0.f,0.f}};

    for (int kc = 0; kc < 4; ++kc) {
        __syncthreads();
        const float4* Ws = (const float4*)(W + kc * 64 * FOUT);
        float4* Wd = (float4*)Wt;
        #pragma unroll
        for (int v = 0; v < 8; ++v) Wd[v * 256 + t] = Ws[v * 256 + t];
        {
            const int hr = t >> 3, hk = (t & 7) * 8;
            const float* hs = h + (size_t)(r0 + hr) * FIN + kc * 64 + hk;
            float4 x0 = *(const float4*)hs;
            float4 x1 = *(const float4*)(hs + 4);
            hT[(hk + 0) * 36 + hr] = x0.x; hT[(hk + 1) * 36 + hr] = x0.y;
            hT[(hk + 2) * 36 + hr] = x0.z; hT[(hk + 3) * 36 + hr] = x0.w;
            hT[(hk + 4) * 36 + hr] = x1.x; hT[(hk + 5) * 36 + hr] = x1.y;
            hT[(hk + 6) * 36 + hr] = x1.z; hT[(hk + 7) * 36 + hr] = x1.w;
        }
        __syncthreads();
        #pragma unroll 8
        for (int kk = 0; kk < 64; ++kk) {
            float4 hv4 = *(const float4*)&hT[kk * 36 + rg * 4];
            float4 wv4 = *(const float4*)&Wt[kk * 128 + cg * 4];
            float hv[4] = {hv4.x, hv4.y, hv4.z, hv4.w};
            float wv[4] = {wv4.x, wv4.y, wv4.z, wv4.w};
            #pragma unroll
            for (int rr = 0; rr < 4; ++rr)
                #pragma unroll
                for (int cc = 0; cc < 4; ++cc)
                    acc[rr][cc] = fmaf(hv[rr], wv[cc], acc[rr][cc]);
        }
    }
    float4 a1v4 = *(const float4*)(a + cg * 4);
    float4 a2v4 = *(const float4*)(a + FOUT + cg * 4);
    float a1v[4] = {a1v4.x, a1v4.y, a1v4.z, a1v4.w};
    float a2v[4] = {a2v4.x, a2v4.y, a2v4.z, a2v4.w};
    float ps[4], qs[4];
    #pragma unroll
    for (int rr = 0; rr < 4; ++rr) {
        float p = 0.f, q = 0.f;
        #pragma unroll
        for (int cc = 0; cc < 4; ++cc) {
            p = fmaf(acc[rr][cc], a1v[cc], p);
            q = fmaf(acc[rr][cc], a2v[cc], q);
        }
        ps[rr] = p; qs[rr] = q;
    }
    #pragma unroll
    for (int off = 1; off <= 16; off <<= 1) {
        #pragma unroll
        for (int rr = 0; rr < 4; ++rr) {
            ps[rr] += __shfl_xor(ps[rr], off);
            qs[rr] += __shfl_xor(qs[rr], off);
        }
    }
    if (cg == 0) {
        #pragma unroll
        for (int rr = 0; rr < 4; ++rr) {
            si[r0 + rg * 4 + rr] = ps[rr];
            sj[r0 + rg * 4 + rr] = qs[rr];
        }
    }
    #pragma unroll
    for (int cc = 0; cc < 4; ++cc) {
        ushort4 v;
        v.x = f2bf(acc[0][cc]); v.y = f2bf(acc[1][cc]);
        v.z = f2bf(acc[2][cc]); v.w = f2bf(acc[3][cc]);
        *(ushort4*)(WhT + (size_t)(cg * 4 + cc) * NN + r0 + rg * 4) = v;
    }
}

// ---------------- K1s: sjmax = max_j sj[j] (global, one scalar) ----------------
__global__ __launch_bounds__(256) void gat_k1s(
    const float* __restrict__ sj, float* __restrict__ sjmax)
{
    __shared__ float red[256];
    float m = -1e30f;
    for (int i = threadIdx.x; i < NN; i += 256) m = fmaxf(m, sj[i]);
    red[threadIdx.x] = m;
    __syncthreads();
    for (int o = 128; o > 0; o >>= 1) {
        if (threadIdx.x < o) red[threadIdx.x] = fmaxf(red[threadIdx.x], red[threadIdx.x + o]);
        __syncthreads();
    }
    if (threadIdx.x == 0) sjmax[0] = red[0];
}

// ---------------- K2: fixed-m masked softmax + P@Wh via MFMA ----------------
// LDS-staged WhT tile (dbuf 2x16KB), 1 barrier/step. Row-sum ls via ones-MFMA.
static __device__ __forceinline__ unsigned short pcalc(
    int a, float sjv, float si_l, float m_row)
{
    float x = si_l + sjv;
    x = fmaxf(x, LALPHA * x);                      // leaky_relu
    float p = (a > 0) ? __expf(x - m_row) : 0.f;   // x <= m_row guaranteed
    return f2bf(p);
}

template<int JS, bool FINAL>
__global__ __launch_bounds__(256, 4) void gat_k2(
    const int* __restrict__ adj, const unsigned short* __restrict__ WhT,
    const float* __restrict__ si, const float* __restrict__ sj,
    const float* __restrict__ sjmaxp,
    float* __restrict__ lsum, float* __restrict__ Opart, float* __restrict__ out)
{
    const int JR_ = NN / JS;
    const int NST_ = JR_ / BKJ;
    __shared__ __align__(16) unsigned short tile[2][8192];   // 2 x 16 KB WhT tile [128c][64j], XOR-swizzled
    const int t = threadIdx.x;
    const int w = t >> 6, l = t & 63;
    const int rb = (int)blockIdx.x / JS, js = (int)blockIdx.x % JS;
    const int iw = rb * 64 + w * 16;       // wave's 16 rows
    const int j0 = js * JR_;
    const int row = l & 15, kg = l >> 4;   // MFMA A-frag: row = l&15, k-slice = kg*8..+8

    const float si_l = si[iw + row];
    const float sjmax = sjmaxp[0];
    const float xm = si_l + sjmax;
    const float m_row = fmaxf(xm, LALPHA * xm);   // upper bound on every masked score of this row
    const float* sjb = sj + j0 + kg * 8;
    const int* adjb = adj + (size_t)(iw + row) * NN + j0 + kg * 8;

    // staging: v=0..3; lane t covers col c=v*32+(t>>3), 16B j-chunk ch=t&7; swz = (c&7)<<4
#define GSRC_D(v) const unsigned short* gsrc##v = WhT + (size_t)(v * 32 + (t >> 3)) * NN + j0 + (t & 7) * 8; \
                  const int ldo##v = ((v * 256 + t) * 16) ^ (((t >> 3) & 7) << 4);
    FOR4(GSRC_D)

#define REG_D(v) int4 stg##v, adr##v;
    FOR4(REG_D)
#define STG_L0(v) stg##v = *(const int4*)(gsrc##v);
    FOR4(STG_L0)
#define ADR_L0(q) adr##q = *(const int4*)(adjb + (q / 2) * 32 + (q % 2) * 4);
    FOR4(ADR_L0)

#define ACC_D(n) f32x4 acc##n = {0.f, 0.f, 0.f, 0.f};
    FOR8(ACC_D)
    f32x4 acc8 = {0.f, 0.f, 0.f, 0.f};    // row-sum accumulator (ones-MFMA)
    bf16x8 ones;
    #pragma unroll
    for (int z = 0; z < 8; ++z) ones[z] = (short)0x3F80;   // bf16 1.0
    const int kg16 = kg * 16;

#define STG_WR(v) *(int4*)((char*)tb + ldo##v) = stg##v;
#define STG_LN(v) stg##v = *(const int4*)(gsrc##v + so);
#define ADR_LN(q) adr##q = *(const int4*)(adjb + so + (q / 2) * 32 + (q % 2) * 4);
#define P8(AF, A0, A1, sp) { \
    float4 s0_ = *(const float4*)(sp); float4 s1_ = *(const float4*)((sp) + 4); \
    AF[0] = (short)pcalc(A0.x, s0_.x, si_l, m_row); \
    AF[1] = (short)pcalc(A0.y, s0_.y, si_l, m_row); \
    AF[2] = (short)pcalc(A0.z, s0_.z, si_l, m_row); \
    AF[3] = (short)pcalc(A0.w, s0_.w, si_l, m_row); \
    AF[4] = (short)pcalc(A1.x, s1_.x, si_l, m_row); \
    AF[5] = (short)pcalc(A1.y, s1_.y, si_l, m_row); \
    AF[6] = (short)pcalc(A1.z, s1_.z, si_l, m_row); \
    AF[7] = (short)pcalc(A1.w, s1_.w, si_l, m_row); }
#define MFMA_ROW(n) { const int c_ = n * 16 + row; \
    const int off_ = c_ * 128 + ((KB ^ ((c_ & 7) << 4))); \
    bf16x8 bv_ = *(const bf16x8*)((const char*)tb + off_); \
    acc##n = __builtin_amdgcn_mfma_f32_16x16x32_bf16(AFk, bv_, acc##n, 0, 0, 0); }
#define MFMA_KC(afv, kcl) { const bf16x8 AFk = afv; const int KB = kcl * 64 + kg16; FOR8(MFMA_ROW) \
    acc8 = __builtin_amdgcn_mfma_f32_16x16x32_bf16(AFk, ones, acc8, 0, 0, 0); }

    for (int s = 0; s < NST_; ++s) {
        unsigned short* tb = tile[s & 1];
        // A: write staged WhT tile (swizzled b128 writes)
        FOR4(STG_WR)
        // B: issue next stage loads (regs now free)
        if (s + 1 < NST_) {
            const size_t so = (size_t)(s + 1) * BKJ;
            FOR4(STG_LN)
        }
        // C: scores -> p (bf16) inline
        bf16x8 af0, af1;
        {
            const float* spp = sjb + s * BKJ;
            P8(af0, adr0, adr1, spp)
            P8(af1, adr2, adr3, spp + 32)
        }
        // D: issue next adj loads
        if (s + 1 < NST_) {
            const size_t so = (size_t)(s + 1) * BKJ;
            FOR4(ADR_LN)
        }
        __syncthreads();   // tile[cur] written by all waves; prior-step reads done
        // F: MFMA 2 k-chunks x (8 col-tiles + 1 ones row-sum)
        MFMA_KC(af0, 0) MFMA_KC(af1, 1)
    }

    // acc8[q] = rowsum for row iw + kg*4 + q (identical across the 16 col-lanes)
    if (FINAL) {
#define FN_ROW(n) { size_t ob = (size_t)(iw + kg * 4) * FOUT + n * 16 + row; \
    float o0 = acc##n[0] / acc8[0]; out[ob]            = (o0 > 0.f) ? o0 : expm1f(o0); \
    float o1 = acc##n[1] / acc8[1]; out[ob + FOUT]     = (o1 > 0.f) ? o1 : expm1f(o1); \
    float o2 = acc##n[2] / acc8[2]; out[ob + 2 * FOUT] = (o2 > 0.f) ? o2 : expm1f(o2); \
    float o3 = acc##n[3] / acc8[3]; out[ob + 3 * FOUT] = (o3 > 0.f) ? o3 : expm1f(o3); }
        FOR8(FN_ROW)
    } else {
        if (row == 0) {
            #pragma unroll
            for (int q = 0; q < 4; ++q)
                lsum[(size_t)js * NN + iw + kg * 4 + q] = acc8[q];
        }
#define ST_ROW(n) { size_t ob = ((size_t)js * NN + iw + kg * 4) * FOUT + n * 16 + row; \
    Opart[ob] = acc##n[0]; Opart[ob + FOUT] = acc##n[1]; \
    Opart[ob + 2 * FOUT] = acc##n[2]; Opart[ob + 3 * FOUT] = acc##n[3]; }
        FOR8(ST_ROW)
    }
}

// ---------------- K3: merge j-splits (plain sums; shared fixed m), divide, ELU ----------------
__global__ __launch_bounds__(256) void gat_k3(
    const float* __restrict__ lsum, const float* __restrict__ Opart,
    float* __restrict__ out)
{
    const int t = threadIdx.x;
    const int i = (int)blockIdx.x * 2 + (t >> 7);
    const int f = t & 127;
    float den = 0.f, num = 0.f;
    const size_t SP = (size_t)NN * FOUT;
    size_t base = (size_t)i * FOUT + f;
    #pragma unroll
    for (int k = 0; k < JSPLIT; ++k) {
        den += lsum[(size_t)k * NN + i];
        num += Opart[(size_t)k * SP + base];
    }
    float o = num / den;
    out[base] = (o > 0.f) ? o : expm1f(o);   // ELU, alpha=1
}

extern "C" void kernel_launch(void* const* d_in, const int* in_sizes, int n_in,
                              void* d_out, int out_size, void* d_ws, size_t ws_size,
                              hipStream_t stream) {
    const float* h  = (const float*)d_in[0];
    const int*  adj = (const int*)d_in[1];
    const float* W  = (const float*)d_in[2];
    const float* a  = (const float*)d_in[3];
    float* out = (float*)d_out;
    char* ws = (char*)d_ws;
    // ws: WhT 2MB | si 32KB | sj 32KB | sjmax 256B | lsum 8*32KB | Opart 8*4MB
    unsigned short* WhT = (unsigned short*)ws;
    float* si     = (float*)(ws + 2097152);
    float* sj     = (float*)(ws + 2129920);
    float* sjmax  = (float*)(ws + 2162688);
    float* lsum   = (float*)(ws + 2162944);
    float* Opart  = (float*)(ws + 2425088);
    const size_t need = 2425088 + (size_t)JSPLIT * NN * FOUT * 4;   // ~36 MB

    gat_k1<<<256, 256, 0, stream>>>(h, W, a, WhT, si, sj);
    gat_k1s<<<1, 256, 0, stream>>>(sj, sjmax);
    if (ws_size >= need) {
        gat_k2<JSPLIT, false><<<128 * JSPLIT, 256, 0, stream>>>(adj, WhT, si, sj, sjmax, lsum, Opart, out);
        gat_k3<<<4096, 256, 0, stream>>>(lsum, Opart, out);
    } else {
        gat_k2<1, true><<<128, 256, 0, stream>>>(adj, WhT, si, sj, sjmax, lsum, Opart, out);
    }
}

// Round 8
// 98.023 us; speedup vs baseline: 1.8800x; 1.1331x over previous
//
#include <hip/hip_runtime.h>

#define NN 8192
#define FIN 256
#define FOUT 128
#define BKJ 128            /* j per step */
#define JSPLIT 4
#define LALPHA 0.2f
#define NEGB -9.0e15f
#define LOG2E 1.4426950408889634f

typedef short bf16x8 __attribute__((ext_vector_type(8)));
typedef float f32x4 __attribute__((ext_vector_type(4)));

#define FOR8(X) X(0) X(1) X(2) X(3) X(4) X(5) X(6) X(7)

static __device__ __forceinline__ unsigned short f2bf(float f) {
    unsigned u = __float_as_uint(f);
    u += 0x7FFFu + ((u >> 16) & 1u);   // RNE
    return (unsigned short)(u >> 16);
}
static __device__ __forceinline__ float ex2(float x) {
    float r; asm("v_exp_f32 %0, %1" : "=v"(r) : "v"(x)); return r;
}
static __device__ __forceinline__ int cvtpk(float lo, float hi) {
    int r; asm("v_cvt_pk_bf16_f32 %0, %1, %2" : "=v"(r) : "v"(lo), "v"(hi)); return r;
}

// ---------------- K1: Wh = h@W (f32), si = Wh@a1, sj = Wh@a2 (+sjl = sj*log2e), WhT bf16 ----------------
__global__ __launch_bounds__(256) void gat_k1(
    const float* __restrict__ h, const float* __restrict__ W,
    const float* __restrict__ a, unsigned short* __restrict__ WhT,
    float* __restrict__ si, float* __restrict__ sj, float* __restrict__ sjl)
{
    __shared__ float Wt[64 * 128];          // 32 KB: W chunk [64k][128c]
    __shared__ float hT[64 * 36 + 4];       // 9 KB: h chunk transposed [64k][32r] pad 36
    const int t = threadIdx.x;
    const int r0 = blockIdx.x * 32;
    const int rg = t >> 5;    // rows rg*4..+4
    const int cg = t & 31;    // cols cg*4..+4
    float acc[4][4] = {{0.f,0.f,0.f,0.f},{0.f,0.f,0.f,0.f},{0.f,0.f,0.f,0.f},{0.f,0.f,0.f,0.f}};

    for (int kc = 0; kc < 4; ++kc) {
        __syncthreads();
        const float4* Ws = (const float4*)(W + kc * 64 * FOUT);
        float4* Wd = (float4*)Wt;
        #pragma unroll
        for (int v = 0; v < 8; ++v) Wd[v * 256 + t] = Ws[v * 256 + t];
        {
            const int hr = t >> 3, hk = (t & 7) * 8;
            const float* hs = h + (size_t)(r0 + hr) * FIN + kc * 64 + hk;
            float4 x0 = *(const float4*)hs;
            float4 x1 = *(const float4*)(hs + 4);
            hT[(hk + 0) * 36 + hr] = x0.x; hT[(hk + 1) * 36 + hr] = x0.y;
            hT[(hk + 2) * 36 + hr] = x0.z; hT[(hk + 3) * 36 + hr] = x0.w;
            hT[(hk + 4) * 36 + hr] = x1.x; hT[(hk + 5) * 36 + hr] = x1.y;
            hT[(hk + 6) * 36 + hr] = x1.z; hT[(hk + 7) * 36 + hr] = x1.w;
        }
        __syncthreads();
        #pragma unroll 8
        for (int kk = 0; kk < 64; ++kk) {
            float4 hv4 = *(const float4*)&hT[kk * 36 + rg * 4];
            float4 wv4 = *(const float4*)&Wt[kk * 128 + cg * 4];
            float hv[4] = {hv4.x, hv4.y, hv4.z, hv4.w};
            float wv[4] = {wv4.x, wv4.y, wv4.z, wv4.w};
            #pragma unroll
            for (int rr = 0; rr < 4; ++rr)
                #pragma unroll
                for (int cc = 0; cc < 4; ++cc)
                    acc[rr][cc] = fmaf(hv[rr], wv[cc], acc[rr][cc]);
        }
    }
    float4 a1v4 = *(const float4*)(a + cg * 4);
    float4 a2v4 = *(const float4*)(a + FOUT + cg * 4);
    float a1v[4] = {a1v4.x, a1v4.y, a1v4.z, a1v4.w};
    float a2v[4] = {a2v4.x, a2v4.y, a2v4.z, a2v4.w};
    float ps[4], qs[4];
    #pragma unroll
    for (int rr = 0; rr < 4; ++rr) {
        float p = 0.f, q = 0.f;
        #pragma unroll
        for (int cc = 0; cc < 4; ++cc) {
            p = fmaf(acc[rr][cc], a1v[cc], p);
            q = fmaf(acc[rr][cc], a2v[cc], q);
        }
        ps[rr] = p; qs[rr] = q;
    }
    #pragma unroll
    for (int off = 1; off <= 16; off <<= 1) {
        #pragma unroll
        for (int rr = 0; rr < 4; ++rr) {
            ps[rr] += __shfl_xor(ps[rr], off);
            qs[rr] += __shfl_xor(qs[rr], off);
        }
    }
    if (cg == 0) {
        #pragma unroll
        for (int rr = 0; rr < 4; ++rr) {
            si[r0 + rg * 4 + rr] = ps[rr];
            sj[r0 + rg * 4 + rr] = qs[rr];
            sjl[r0 + rg * 4 + rr] = qs[rr] * LOG2E;
        }
    }
    #pragma unroll
    for (int cc = 0; cc < 4; ++cc) {
        ushort4 v;
        v.x = f2bf(acc[0][cc]); v.y = f2bf(acc[1][cc]);
        v.z = f2bf(acc[2][cc]); v.w = f2bf(acc[3][cc]);
        *(ushort4*)(WhT + (size_t)(cg * 4 + cc) * NN + r0 + rg * 4) = v;
    }
}

// ---------------- K1s: sjmax = max_j sj[j] (global, one scalar) ----------------
__global__ __launch_bounds__(256) void gat_k1s(
    const float* __restrict__ sj, float* __restrict__ sjmax)
{
    __shared__ float red[256];
    float m = -1e30f;
    for (int i = threadIdx.x; i < NN; i += 256) m = fmaxf(m, sj[i]);
    red[threadIdx.x] = m;
    __syncthreads();
    for (int o = 128; o > 0; o >>= 1) {
        if (threadIdx.x < o) red[threadIdx.x] = fmaxf(red[threadIdx.x], red[threadIdx.x + o]);
        __syncthreads();
    }
    if (threadIdx.x == 0) sjmax[0] = red[0];
}

// ---------------- K2: fixed-m masked softmax (exp2 domain) + P@Wh via MFMA ----------------
// p = 2^( max(a2 + sjl, 0.2*sjl + b2) ) masked; a2=(si-m)*log2e, b2=(0.2*si-m)*log2e.
static __device__ __forceinline__ float pe(int av, float sjlv, float a2, float b2) {
    float t1 = a2 + sjlv;
    float t2 = fmaf(0.2f, sjlv, b2);
    float y = fmaxf(t1, t2);
    y = (av > 0) ? y : NEGB;      // 2^NEGB -> 0
    return ex2(y);
}

template<int JS, bool FINAL>
__global__ __launch_bounds__(256, 2) void gat_k2(
    const int* __restrict__ adj, const unsigned short* __restrict__ WhT,
    const float* __restrict__ si, const float* __restrict__ sjl,
    const float* __restrict__ sjmaxp,
    float* __restrict__ lsum, float* __restrict__ Opart, float* __restrict__ out)
{
    const int JR_ = NN / JS;
    const int NST_ = JR_ / BKJ;
    __shared__ __align__(16) unsigned short tile[2][16384];   // 2 x 32 KB WhT tile [128c][128j], XOR-swizzled
    const int t = threadIdx.x;
    const int w = t >> 6, l = t & 63;
    const int rb = (int)blockIdx.x / JS, js = (int)blockIdx.x % JS;
    const int iw = rb * 64 + w * 16;       // wave's 16 rows
    const int j0 = js * JR_;
    const int row = l & 15, kg = l >> 4;   // MFMA A-frag: row = l&15, k-slice = kg*8..+8

    const float si_l = si[iw + row];
    const float sjmax = sjmaxp[0];
    const float xm = si_l + sjmax;
    const float m_row = fmaxf(xm, LALPHA * xm);   // upper bound on every masked score of this row
    const float a2 = (si_l - m_row) * LOG2E;
    const float b2 = (LALPHA * si_l - m_row) * LOG2E;
    const float* sjb = sjl + j0 + kg * 8;
    const int* adjb = adj + (size_t)(iw + row) * NN + j0 + kg * 8;

    // staging: lane t covers WhT col c=v*16+(t>>4), 16B j-chunk ch=t&15; swz = (c&7)<<4
#define GSRC_D(v) const unsigned short* gsrc##v = WhT + (size_t)(v * 16 + (t >> 4)) * NN + j0 + (t & 15) * 8; \
                  const int ldo##v = ((v * 256 + t) * 16) ^ (((t >> 4) & 7) << 4);
    FOR8(GSRC_D)

#define REG_D(v) int4 stg##v, adr##v;
    FOR8(REG_D)
#define STG_L0(v) stg##v = *(const int4*)(gsrc##v);
    FOR8(STG_L0)
#define ADR_L0(q) adr##q = *(const int4*)(adjb + (q / 2) * 32 + (q % 2) * 4);
    FOR8(ADR_L0)

#define ACC_D(n) f32x4 acc##n = {0.f, 0.f, 0.f, 0.f};
    FOR8(ACC_D)
    f32x4 acc8 = {0.f, 0.f, 0.f, 0.f};    // row-sum accumulator (ones-MFMA)
    bf16x8 ones;
    #pragma unroll
    for (int z = 0; z < 8; ++z) ones[z] = (short)0x3F80;   // bf16 1.0
    const int kg16 = kg * 16;

#define STG_WR(v) *(int4*)((char*)tb + ldo##v) = stg##v;
#define STG_LN(v) stg##v = *(const int4*)(gsrc##v + so);
#define ADR_LN(q) adr##q = *(const int4*)(adjb + so + (q / 2) * 32 + (q % 2) * 4);
#define P8(AF, A0, A1, sp) { \
    float4 s0_ = *(const float4*)(sp); float4 s1_ = *(const float4*)((sp) + 4); \
    float p0_ = pe(A0.x, s0_.x, a2, b2), p1_ = pe(A0.y, s0_.y, a2, b2); \
    float p2_ = pe(A0.z, s0_.z, a2, b2), p3_ = pe(A0.w, s0_.w, a2, b2); \
    float p4_ = pe(A1.x, s1_.x, a2, b2), p5_ = pe(A1.y, s1_.y, a2, b2); \
    float p6_ = pe(A1.z, s1_.z, a2, b2), p7_ = pe(A1.w, s1_.w, a2, b2); \
    int4 w_; w_.x = cvtpk(p0_, p1_); w_.y = cvtpk(p2_, p3_); \
    w_.z = cvtpk(p4_, p5_); w_.w = cvtpk(p6_, p7_); \
    AF = __builtin_bit_cast(bf16x8, w_); }
#define MFMA_ROW(n) { const int c_ = n * 16 + row; \
    const int off_ = c_ * 256 + ((KB ^ ((c_ & 7) << 4))); \
    bf16x8 bv_ = *(const bf16x8*)((const char*)tb + off_); \
    acc##n = __builtin_amdgcn_mfma_f32_16x16x32_bf16(AFk, bv_, acc##n, 0, 0, 0); }
#define MFMA_KC(afv, kcl) { const bf16x8 AFk = afv; const int KB = kcl * 64 + kg16; FOR8(MFMA_ROW) \
    acc8 = __builtin_amdgcn_mfma_f32_16x16x32_bf16(AFk, ones, acc8, 0, 0, 0); }

    for (int s = 0; s < NST_; ++s) {
        unsigned short* tb = tile[s & 1];
        // A: scores -> p (bf16) first (adj for step s arrived a full step ago)
        bf16x8 af0, af1, af2, af3;
        {
            const float* spp = sjb + s * BKJ;
            P8(af0, adr0, adr1, spp)
            P8(af1, adr2, adr3, spp + 32)
            P8(af2, adr4, adr5, spp + 64)
            P8(af3, adr6, adr7, spp + 96)
        }
        // B: issue next adj loads NOW (full-step lead to cover HBM drain)
        if (s + 1 < NST_) {
            const size_t so = (size_t)(s + 1) * BKJ;
            FOR8(ADR_LN)
        }
        // C: write staged WhT tile (swizzled b128 writes)
        FOR8(STG_WR)
        // D: issue next WhT stage loads (L2-fast)
        if (s + 1 < NST_) {
            const size_t so = (size_t)(s + 1) * BKJ;
            FOR8(STG_LN)
        }
        // E: lgkm-only barrier — do NOT drain the in-flight global prefetches
        __builtin_amdgcn_sched_barrier(0);
        asm volatile("s_waitcnt lgkmcnt(0)" ::: "memory");
        __builtin_amdgcn_s_barrier();
        __builtin_amdgcn_sched_barrier(0);
        // F: MFMA 4 k-chunks x (8 col-tiles + 1 ones row-sum)
        MFMA_KC(af0, 0) MFMA_KC(af1, 1) MFMA_KC(af2, 2) MFMA_KC(af3, 3)
    }

    // acc8[q] = rowsum for row iw + kg*4 + q (identical across the 16 col-lanes)
    if (FINAL) {
#define FN_ROW(n) { size_t ob = (size_t)(iw + kg * 4) * FOUT + n * 16 + row; \
    float o0 = acc##n[0] / acc8[0]; out[ob]            = (o0 > 0.f) ? o0 : expm1f(o0); \
    float o1 = acc##n[1] / acc8[1]; out[ob + FOUT]     = (o1 > 0.f) ? o1 : expm1f(o1); \
    float o2 = acc##n[2] / acc8[2]; out[ob + 2 * FOUT] = (o2 > 0.f) ? o2 : expm1f(o2); \
    float o3 = acc##n[3] / acc8[3]; out[ob + 3 * FOUT] = (o3 > 0.f) ? o3 : expm1f(o3); }
        FOR8(FN_ROW)
    } else {
        if (row == 0) {
            #pragma unroll
            for (int q = 0; q < 4; ++q)
                lsum[(size_t)js * NN + iw + kg * 4 + q] = acc8[q];
        }
#define ST_ROW(n) { size_t ob = ((size_t)js * NN + iw + kg * 4) * FOUT + n * 16 + row; \
    Opart[ob] = acc##n[0]; Opart[ob + FOUT] = acc##n[1]; \
    Opart[ob + 2 * FOUT] = acc##n[2]; Opart[ob + 3 * FOUT] = acc##n[3]; }
        FOR8(ST_ROW)
    }
}

// ---------------- K3: merge j-splits (plain sums; shared fixed m), divide, ELU ----------------
__global__ __launch_bounds__(256) void gat_k3(
    const float* __restrict__ lsum, const float* __restrict__ Opart,
    float* __restrict__ out)
{
    const int t = threadIdx.x;
    const int i = (int)blockIdx.x * 2 + (t >> 7);
    const int f = t & 127;
    float den = 0.f, num = 0.f;
    const size_t SP = (size_t)NN * FOUT;
    size_t base = (size_t)i * FOUT + f;
    #pragma unroll
    for (int k = 0; k < JSPLIT; ++k) {
        den += lsum[(size_t)k * NN + i];
        num += Opart[(size_t)k * SP + base];
    }
    float o = num / den;
    out[base] = (o > 0.f) ? o : expm1f(o);   // ELU, alpha=1
}

extern "C" void kernel_launch(void* const* d_in, const int* in_sizes, int n_in,
                              void* d_out, int out_size, void* d_ws, size_t ws_size,
                              hipStream_t stream) {
    const float* h  = (const float*)d_in[0];
    const int*  adj = (const int*)d_in[1];
    const float* W  = (const float*)d_in[2];
    const float* a  = (const float*)d_in[3];
    float* out = (float*)d_out;
    char* ws = (char*)d_ws;
    // ws: WhT 2MB | si 32KB | sj 32KB | sjl 32KB | sjmax 256B | lsum 4*32KB | Opart 4*4MB
    unsigned short* WhT = (unsigned short*)ws;
    float* si     = (float*)(ws + 2097152);
    float* sj     = (float*)(ws + 2129920);
    float* sjl    = (float*)(ws + 2162688);
    float* sjmax  = (float*)(ws + 2195456);
    float* lsum   = (float*)(ws + 2195712);
    float* Opart  = (float*)(ws + 2326784);
    const size_t need = 2326784 + (size_t)JSPLIT * NN * FOUT * 4;   // ~19.1 MB

    gat_k1<<<256, 256, 0, stream>>>(h, W, a, WhT, si, sj, sjl);
    gat_k1s<<<1, 256, 0, stream>>>(sj, sjmax);
    if (ws_size >= need) {
        gat_k2<JSPLIT, false><<<128 * JSPLIT, 256, 0, stream>>>(adj, WhT, si, sjl, sjmax, lsum, Opart, out);
        gat_k3<<<4096, 256, 0, stream>>>(lsum, Opart, out);
    } else {
        gat_k2<1, true><<<128, 256, 0, stream>>>(adj, WhT, si, sjl, sjmax, lsum, Opart, out);
    }
}